// Round 10
// baseline (2793.288 us; speedup 1.0000x reference)
//
#include <hip/hip_runtime.h>
#include <hip/hip_bf16.h>

// N=100000, E=1600000.
// R10: encoder reworked -- bf16-packed K/V slab (2 LDS reads/token for both
// heads), streaming FFN (no hbuf[24]), __launch_bounds__(256,5) to cap VGPR.

#define NEG_SLOPE 0.2f

__device__ __forceinline__ float bf_lo(unsigned u) { return __uint_as_float(u << 16); }
__device__ __forceinline__ float bf_hi(unsigned u) { return __uint_as_float(u & 0xffff0000u); }
__device__ __forceinline__ unsigned pk(float lo, float hi)
{
    __hip_bfloat16 l = __float2bfloat16(lo), h = __float2bfloat16(hi);
    unsigned ul = reinterpret_cast<unsigned short&>(l);
    unsigned uh = reinterpret_cast<unsigned short&>(h);
    return ul | (uh << 16);
}

// ---------------------------------------------------------------------------
// Encoder: 8 nodes/block, 32 lanes/node. K/V staged as bf16 (32B/token).
// ---------------------------------------------------------------------------
__global__ void __launch_bounds__(256, 5) encoder_kernel(
    const float* __restrict__ Xf,
    const float* __restrict__ Wq, const float* __restrict__ bq,
    const float* __restrict__ Wk, const float* __restrict__ bk,
    const float* __restrict__ Wv, const float* __restrict__ bv,
    const float* __restrict__ g0, const float* __restrict__ be0,
    const float* __restrict__ Wf1, const float* __restrict__ bf1,
    const float* __restrict__ Wf2, const float* __restrict__ bf2,
    const float* __restrict__ g1, const float* __restrict__ be1,
    const float* __restrict__ Wrep, const float* __restrict__ brep,
    float* __restrict__ xt, int n)
{
    __shared__ float sh[2560];
    int t = threadIdx.x;
    int bid = blockIdx.x;
    size_t base = (size_t)bid * 2560;
#pragma unroll
    for (int i = 0; i < 10; ++i) sh[i * 256 + t] = Xf[base + i * 256 + t];
    __syncthreads();

    int sub = t >> 5;
    int s   = t & 31;
    int v   = bid * 8 + sub;

    float xv[10];
#pragma unroll
    for (int i = 0; i < 10; ++i) xv[i] = sh[sub * 320 + s * 10 + i];
    __syncthreads();   // Xf consumed; slab reused for bf16 K/V

    float q[6], k[6], w[6];
#pragma unroll
    for (int j = 0; j < 6; ++j) { q[j] = bq[j]; k[j] = bk[j]; w[j] = bv[j]; }
#pragma unroll
    for (int i = 0; i < 10; ++i) {
#pragma unroll
        for (int j = 0; j < 6; ++j) {
            q[j] += xv[i] * Wq[i * 6 + j];
            k[j] += xv[i] * Wk[i * 6 + j];
            w[j] += xv[i] * Wv[i * 6 + j];
        }
    }

    // K/V slab: per node 32 tokens x 2 uint4 (k01,k23,k45,v01 | v23,v45,-,-).
    // Same-wave producer/consumer only.
    uint4* shu = (uint4*)sh;
    int nb = sub * 64;                       // node base in uint4 units
    shu[nb + s * 2]     = make_uint4(pk(k[0], k[1]), pk(k[2], k[3]),
                                     pk(k[4], k[5]), pk(w[0], w[1]));
    shu[nb + s * 2 + 1] = make_uint4(pk(w[2], w[3]), pk(w[4], w[5]), 0u, 0u);
    __builtin_amdgcn_wave_barrier();

    // logits |.| << 1 -> no max subtraction needed
    const float scale = 0.40824829046386301637f;  // 1/sqrt(6)
    float q0s = q[0] * scale, q1s = q[1] * scale, q2s = q[2] * scale;
    float q3s = q[3] * scale, q4s = q[4] * scale, q5s = q[5] * scale;

    float dA0 = 0.f, dB0 = 0.f, dA1 = 0.f, dB1 = 0.f;
    float aA00 = 0.f, aA01 = 0.f, aA02 = 0.f;
    float aB00 = 0.f, aB01 = 0.f, aB02 = 0.f;
    float aA10 = 0.f, aA11 = 0.f, aA12 = 0.f;
    float aB10 = 0.f, aB11 = 0.f, aB12 = 0.f;

#pragma unroll
    for (int t2 = 0; t2 < 32; t2 += 2) {
        uint4 Ua = shu[nb + t2 * 2];
        uint4 Ub = shu[nb + t2 * 2 + 1];
        uint4 Uc = shu[nb + t2 * 2 + 2];
        uint4 Ud = shu[nb + t2 * 2 + 3];
        // token t2
        {
            float k0 = bf_lo(Ua.x), k1 = bf_hi(Ua.x);
            float k2 = bf_lo(Ua.y), k3 = bf_hi(Ua.y);
            float k4 = bf_lo(Ua.z), k5 = bf_hi(Ua.z);
            float v0 = bf_lo(Ua.w), v1 = bf_hi(Ua.w);
            float v2 = bf_lo(Ub.x), v3 = bf_hi(Ub.x);
            float v4 = bf_lo(Ub.y), v5 = bf_hi(Ub.y);
            float p0 = __expf(q0s * k0 + q1s * k1 + q2s * k2);
            float p1 = __expf(q3s * k3 + q4s * k4 + q5s * k5);
            dA0 += p0; aA00 += p0 * v0; aA01 += p0 * v1; aA02 += p0 * v2;
            dA1 += p1; aA10 += p1 * v3; aA11 += p1 * v4; aA12 += p1 * v5;
        }
        // token t2+1
        {
            float k0 = bf_lo(Uc.x), k1 = bf_hi(Uc.x);
            float k2 = bf_lo(Uc.y), k3 = bf_hi(Uc.y);
            float k4 = bf_lo(Uc.z), k5 = bf_hi(Uc.z);
            float v0 = bf_lo(Uc.w), v1 = bf_hi(Uc.w);
            float v2 = bf_lo(Ud.x), v3 = bf_hi(Ud.x);
            float v4 = bf_lo(Ud.y), v5 = bf_hi(Ud.y);
            float p0 = __expf(q0s * k0 + q1s * k1 + q2s * k2);
            float p1 = __expf(q3s * k3 + q4s * k4 + q5s * k5);
            dB0 += p0; aB00 += p0 * v0; aB01 += p0 * v1; aB02 += p0 * v2;
            dB1 += p1; aB10 += p1 * v3; aB11 += p1 * v4; aB12 += p1 * v5;
        }
    }

    float O[6];
    {
        float inv0 = 1.f / (dA0 + dB0);
        float inv1 = 1.f / (dA1 + dB1);
        O[0] = q[0] + (aA00 + aB00) * inv0;
        O[1] = q[1] + (aA01 + aB01) * inv0;
        O[2] = q[2] + (aA02 + aB02) * inv0;
        O[3] = q[3] + (aA10 + aB10) * inv1;
        O[4] = q[4] + (aA11 + aB11) * inv1;
        O[5] = q[5] + (aA12 + aB12) * inv1;
    }

    // LayerNorm(g0, be0)
    {
        float mean = (O[0] + O[1] + O[2] + O[3] + O[4] + O[5]) * (1.f / 6.f);
        float var = 0.f;
#pragma unroll
        for (int j = 0; j < 6; ++j) { float d = O[j] - mean; var += d * d; }
        var *= (1.f / 6.f);
        float r = rsqrtf(var + 1e-5f);
#pragma unroll
        for (int j = 0; j < 6; ++j) O[j] = (O[j] - mean) * r * g0[j] + be0[j];
    }

    // streaming FFN 6->24->6 (no hidden buffer) + residual
    float f[6];
#pragma unroll
    for (int j = 0; j < 6; ++j) f[j] = O[j] + bf2[j];
#pragma unroll
    for (int r = 0; r < 24; ++r) {
        float hr = bf1[r];
#pragma unroll
        for (int j = 0; j < 6; ++j) hr += O[j] * Wf1[j * 24 + r];
        hr = fmaxf(hr, 0.f);
#pragma unroll
        for (int j = 0; j < 6; ++j) f[j] += hr * Wf2[r * 6 + j];
    }
    // LayerNorm(g1, be1)
    {
        float mean = (f[0] + f[1] + f[2] + f[3] + f[4] + f[5]) * (1.f / 6.f);
        float var = 0.f;
#pragma unroll
        for (int j = 0; j < 6; ++j) { float d = f[j] - mean; var += d * d; }
        var *= (1.f / 6.f);
        float r = rsqrtf(var + 1e-5f);
#pragma unroll
        for (int j = 0; j < 6; ++j) f[j] = (f[j] - mean) * r * g1[j] + be1[j];
    }

    float wr = Wrep[s];
#pragma unroll
    for (int j = 0; j < 6; ++j) {
        float val = f[j] * wr;
#pragma unroll
        for (int off = 16; off >= 1; off >>= 1) val += __shfl_xor(val, off, 32);
        f[j] = val;
    }
    if (s == 0) {
        float br = brep[0];
#pragma unroll
        for (int j = 0; j < 6; ++j) xt[(size_t)v * 6 + j] = f[j] + br;
    }
}

// ---------------------------------------------------------------------------
// xw1 = x @ W1 -> bf16 table (N,64); ai1 fp32 dots (N,8). 16 nodes/block.
// ---------------------------------------------------------------------------
__global__ void __launch_bounds__(256) xw1_kernel(
    const float* __restrict__ x, const float* __restrict__ W1,
    const float* __restrict__ att1,
    __hip_bfloat16* __restrict__ xwb,
    float* __restrict__ ai, int n)
{
    __shared__ float shW[4096];
    __shared__ float shX[256];
    int t = threadIdx.x, wv = t >> 6, l = t & 63;
#pragma unroll
    for (int i = 0; i < 16; ++i) shW[i * 256 + t] = W1[i * 256 + t];
    int h = l >> 3, c = l & 7;
    float a_i = att1[h * 16 + c];
    __syncthreads();

#pragma unroll
    for (int it = 0; it < 4; ++it) {
        int v = blockIdx.x * 16 + it * 4 + wv;
        shX[wv * 64 + l] = x[(size_t)v * 64 + l];
        __builtin_amdgcn_wave_barrier();
        float acc = 0.f;
#pragma unroll
        for (int k4 = 0; k4 < 16; ++k4) {
            float4 xb4 = *(const float4*)&shX[wv * 64 + k4 * 4];
            acc += xb4.x * shW[(k4 * 4 + 0) * 64 + l];
            acc += xb4.y * shW[(k4 * 4 + 1) * 64 + l];
            acc += xb4.z * shW[(k4 * 4 + 2) * 64 + l];
            acc += xb4.w * shW[(k4 * 4 + 3) * 64 + l];
        }
        xwb[(size_t)v * 64 + l] = __float2bfloat16(acc);

        float pi = acc * a_i;
#pragma unroll
        for (int off = 1; off < 8; off <<= 1)
            pi += __shfl_xor(pi, off, 64);
        if (c == 0) ai[(size_t)v * 8 + h] = pi;
        __builtin_amdgcn_wave_barrier();
    }
}

// ---------------------------------------------------------------------------
// CSR build: count -> 3-kernel scan -> scatter
// ---------------------------------------------------------------------------
__global__ void count_kernel(const int* __restrict__ src, const int* __restrict__ dst,
                             int* __restrict__ deg, int e)
{
    int i = blockIdx.x * blockDim.x + threadIdx.x;
    if (i < e) {
        int s = src[i], d = dst[i];
        if (s != d) atomicAdd(&deg[d], 1);
    }
}

__global__ void __launch_bounds__(1024) scan1_kernel(
    const int* __restrict__ deg, int* __restrict__ bsum, int n)
{
    __shared__ int sh[1024];
    int t = threadIdx.x;
    int i = blockIdx.x * 1024 + t;
    sh[t] = (i < n) ? deg[i] : 0;
    __syncthreads();
    for (int off = 512; off >= 1; off >>= 1) {
        if (t < off) sh[t] += sh[t + off];
        __syncthreads();
    }
    if (t == 0) bsum[blockIdx.x] = sh[0];
}

__global__ void __launch_bounds__(128) scan2_kernel(int* __restrict__ bsum, int nb)
{
    __shared__ int sh[128];
    int t = threadIdx.x;
    int v = (t < nb) ? bsum[t] : 0;
    sh[t] = v;
    __syncthreads();
    for (int off = 1; off < 128; off <<= 1) {
        int val = (t >= off) ? sh[t - off] : 0;
        __syncthreads();
        sh[t] += val;
        __syncthreads();
    }
    if (t < nb) bsum[t] = sh[t] - v;   // exclusive
}

__global__ void __launch_bounds__(1024) scan3_kernel(
    const int* __restrict__ deg, const int* __restrict__ bsum,
    int* __restrict__ offs, int n)
{
    __shared__ int sh[1024];
    int t = threadIdx.x;
    int i = blockIdx.x * 1024 + t;
    int v = (i < n) ? deg[i] : 0;
    sh[t] = v;
    __syncthreads();
    for (int off = 1; off < 1024; off <<= 1) {
        int val = (t >= off) ? sh[t - off] : 0;
        __syncthreads();
        sh[t] += val;
        __syncthreads();
    }
    if (i < n) offs[i] = bsum[blockIdx.x] + sh[t] - v;
}

__global__ void scatter_kernel(const int* __restrict__ src, const int* __restrict__ dst,
                               const int* __restrict__ offsets, int* __restrict__ cursor,
                               int* __restrict__ elist, int e)
{
    int i = blockIdx.x * blockDim.x + threadIdx.x;
    if (i < e) {
        int s = src[i], d = dst[i];
        if (s != d) {
            int pos = offsets[d] + atomicAdd(&cursor[d], 1);
            elist[pos] = s;
        }
    }
}

// ---------------------------------------------------------------------------
// PURE GAT-1 aggregation: ONE node per wave, ZERO LDS, no block barrier.
// Per edge: 1 row gather (128B line); aj1 recomputed via 3 shfl_xor.
// ---------------------------------------------------------------------------
__global__ void __launch_bounds__(256) agg1_kernel(
    const __hip_bfloat16* __restrict__ xwb, const float* __restrict__ ai1,
    const float* __restrict__ att1, const float* __restrict__ b1,
    const int* __restrict__ offs, const int* __restrict__ deg,
    const int* __restrict__ elist,
    __hip_bfloat16* __restrict__ h1b, int n)
{
    int t = threadIdx.x, wv = t >> 6, l = t & 63;
    int v = blockIdx.x * 4 + wv;
    int h = l >> 3, c = l & 7;
    float attj_l = att1[h * 16 + 8 + c];   // a_j[h][c]
    float ai_l = ai1[(size_t)v * 8 + h];

    float yself = __bfloat162float(xwb[(size_t)v * 64 + l]);
    float ps = yself * attj_l;
    ps += __shfl_xor(ps, 1, 64);
    ps += __shfl_xor(ps, 2, 64);
    ps += __shfl_xor(ps, 4, 64);
    float a = ai_l + ps;
    a = a >= 0.f ? a : NEG_SLOPE * a;
    float ea  = __expf(a);
    float acc = ea * yself;
    float den = ea;

    int off = offs[v], dg = deg[v];
    for (int j = 0; j < dg; j += 16) {
        int idxv = 0;
        if (l < 16 && j + l < dg) idxv = elist[off + j + l];
#pragma unroll
        for (int b = 0; b < 16; ++b) {
            int s = __shfl(idxv, b, 64);
            float y = __bfloat162float(xwb[(size_t)s * 64 + l]);
            float pp = y * attj_l;
            pp += __shfl_xor(pp, 1, 64);
            pp += __shfl_xor(pp, 2, 64);
            pp += __shfl_xor(pp, 4, 64);     // aj1[s][h] on all 8 lanes of head
            float aa = ai_l + pp;
            aa = aa >= 0.f ? aa : NEG_SLOPE * aa;
            float w = (j + b < dg) ? __expf(aa) : 0.f;  // scalar condition
            acc += w * y;
            den += w;
        }
    }

    float o = acc / den + b1[l];
    o = o > 0.f ? o : expm1f(o);   // elu
    h1b[(size_t)v * 64 + l] = __float2bfloat16(o);
}

// ---------------------------------------------------------------------------
// xw2pack: packed xw2 rows [80 bf16 | 8 bf16 aj2 | pad] stride 128 u16, + ai2.
// 16 nodes/block (4 per wave), W2 staged once per block.
// ---------------------------------------------------------------------------
__global__ void __launch_bounds__(256) xw2pack_kernel(
    const __hip_bfloat16* __restrict__ h1b, const float* __restrict__ xt,
    const float* __restrict__ W2, const float* __restrict__ att2,
    __hip_bfloat16* __restrict__ xw2p, float* __restrict__ ai2, int n)
{
    __shared__ float shW2[5600];
    __shared__ float shH[4][72];
    __shared__ float shR[4][80];
    int t = threadIdx.x, wv = t >> 6, l = t & 63;
    for (int i = t; i < 5600; i += 256) shW2[i] = W2[i];
    __syncthreads();

#pragma unroll
    for (int it = 0; it < 4; ++it) {
        int v = blockIdx.x * 16 + it * 4 + wv;

        shH[wv][l] = __bfloat162float(h1b[(size_t)v * 64 + l]);
        if (l < 6) shH[wv][64 + l] = xt[(size_t)v * 6 + l];
        __builtin_amdgcn_wave_barrier();

        float a0 = 0.f, a1 = 0.f;
#pragma unroll
        for (int kk = 0; kk < 70; ++kk) {
            float f = shH[wv][kk];
            a0 += f * shW2[kk * 80 + l];
            if (l < 16) a1 += f * shW2[kk * 80 + 64 + l];
        }
        __hip_bfloat16* row = xw2p + (size_t)v * 128;
        row[l] = __float2bfloat16(a0);
        shR[wv][l] = a0;
        if (l < 16) {
            row[64 + l] = __float2bfloat16(a1);
            shR[wv][64 + l] = a1;
        }
        __builtin_amdgcn_wave_barrier();

        if (l < 16) {
            int hh = l >> 1, wj = l & 1;
            float sdot = 0.f;
#pragma unroll
            for (int cc = 0; cc < 10; ++cc)
                sdot += shR[wv][hh * 10 + cc] * att2[hh * 20 + wj * 10 + cc];
            if (wj == 0) ai2[(size_t)v * 8 + hh] = sdot;
            else         row[80 + hh] = __float2bfloat16(sdot);  // aj2 packed
        }
        __builtin_amdgcn_wave_barrier();
    }
}

// ---------------------------------------------------------------------------
// GAT layer 2 aggregation on packed rows + head-mean + b2 + log_softmax.
// One node per wave; 1 u32 gather per edge (44 lanes) + 1 shfl.
// ---------------------------------------------------------------------------
__global__ void __launch_bounds__(256) agg2_kernel(
    const unsigned* __restrict__ xw2p, const float* __restrict__ ai2,
    const float* __restrict__ b2,
    const int* __restrict__ offs, const int* __restrict__ deg,
    const int* __restrict__ elist, float* __restrict__ out, int n)
{
    __shared__ float buf[4][80];
    __shared__ float buf2[4][10];
    int t = threadIdx.x, wv = t >> 6, l = t & 63;
    int v = blockIdx.x * 4 + wv;

    bool act = l < 44;
    int hc = (l < 40) ? (l / 5) : 0;       // head of cols (2l, 2l+1)
    int ajl = 40 + (hc >> 1);              // holder lane of aj pair
    float ai_l = (l < 40) ? ai2[(size_t)v * 8 + hc] : 0.f;

    unsigned selfw = 0;
    if (act) selfw = xw2p[(size_t)v * 64 + l];
    unsigned ajw = __shfl(selfw, ajl, 64);
    float ajs = (hc & 1) ? bf_hi(ajw) : bf_lo(ajw);
    float a = ai_l + ajs;
    a = a >= 0.f ? a : NEG_SLOPE * a;
    float e0 = __expf(a);
    float acc0 = e0 * bf_lo(selfw), acc1 = e0 * bf_hi(selfw), den = e0;

    int off = offs[v], dg = deg[v];
    for (int j = 0; j < dg; j += 16) {
        int idxv = 0;
        if (l < 16 && j + l < dg) idxv = elist[off + j + l];
#pragma unroll
        for (int b = 0; b < 16; ++b) {
            int s = __shfl(idxv, b, 64);
            unsigned yw = 0;
            if (act) yw = xw2p[(size_t)s * 64 + l];
            unsigned aw = __shfl(yw, ajl, 64);
            float aj = (hc & 1) ? bf_hi(aw) : bf_lo(aw);
            float u = ai_l + aj;
            u = u >= 0.f ? u : NEG_SLOPE * u;
            float w = (j + b < dg) ? __expf(u) : 0.f;   // scalar condition
            acc0 += w * bf_lo(yw);
            acc1 += w * bf_hi(yw);
            den += w;
        }
    }

    if (l < 40) {
        float inv = 1.f / den;
        buf[wv][2 * l]     = acc0 * inv;
        buf[wv][2 * l + 1] = acc1 * inv;
    }
    __builtin_amdgcn_wave_barrier();
    if (l < 10) {
        float mval = 0.f;
#pragma unroll
        for (int hh = 0; hh < 8; ++hh) mval += buf[wv][hh * 10 + l];
        buf2[wv][l] = mval * 0.125f + b2[l];
    }
    __builtin_amdgcn_wave_barrier();
    if (l < 10) {
        float mx = -1e30f;
#pragma unroll
        for (int cc = 0; cc < 10; ++cc) mx = fmaxf(mx, buf2[wv][cc]);
        float se = 0.f;
#pragma unroll
        for (int cc = 0; cc < 10; ++cc) se += __expf(buf2[wv][cc] - mx);
        out[(size_t)v * 10 + l] = buf2[wv][l] - mx - __logf(se);
    }
}

// ---------------------------------------------------------------------------
extern "C" void kernel_launch(void* const* d_in, const int* in_sizes, int n_in,
                              void* d_out, int out_size, void* d_ws, size_t ws_size,
                              hipStream_t stream)
{
    const float* x    = (const float*)d_in[0];
    const int*   ei   = (const int*)  d_in[1];
    const float* ef   = (const float*)d_in[2];
    const float* W1   = (const float*)d_in[3];
    const float* att1 = (const float*)d_in[4];
    const float* b1   = (const float*)d_in[5];
    const float* W2   = (const float*)d_in[6];
    const float* att2 = (const float*)d_in[7];
    const float* b2   = (const float*)d_in[8];
    const float* Wq   = (const float*)d_in[9];
    const float* bq   = (const float*)d_in[10];
    const float* Wk   = (const float*)d_in[11];
    const float* bk   = (const float*)d_in[12];
    const float* Wv   = (const float*)d_in[13];
    const float* bv   = (const float*)d_in[14];
    const float* g0   = (const float*)d_in[15];
    const float* be0  = (const float*)d_in[16];
    const float* Wf1  = (const float*)d_in[17];
    const float* bf1  = (const float*)d_in[18];
    const float* Wf2  = (const float*)d_in[19];
    const float* bf2  = (const float*)d_in[20];
    const float* g1   = (const float*)d_in[21];
    const float* be1  = (const float*)d_in[22];
    const float* Wrep = (const float*)d_in[23];
    const float* brep = (const float*)d_in[24];

    const int n = in_sizes[0] / 64;   // 100000
    const int e = in_sizes[1] / 2;    // 1600000
    const int* src = ei;
    const int* dst = ei + e;

    char* ws = (char*)d_ws;
    size_t o = 0;
    auto alloc = [&](size_t bytes) -> void* {
        void* p = ws + o;
        o += (bytes + 255) & ~(size_t)255;
        return p;
    };
    __hip_bfloat16* xw1b = (__hip_bfloat16*)alloc((size_t)n * 64 * 2);
    __hip_bfloat16* h1b  = (__hip_bfloat16*)alloc((size_t)n * 64 * 2);
    __hip_bfloat16* xw2p = (__hip_bfloat16*)alloc((size_t)n * 128 * 2); // packed
    float* ai1   = (float*)alloc((size_t)n * 8 * 4);
    float* ai2   = (float*)alloc((size_t)n * 8 * 4);
    float* xt    = (float*)alloc((size_t)n * 6 * 4);
    int*   deg   = (int*)  alloc((size_t)n * 4);
    int*   offs  = (int*)  alloc((size_t)n * 4);
    int*   cur   = (int*)  alloc((size_t)n * 4);
    int*   bsum  = (int*)  alloc(256 * 4);
    int*   elist = (int*)  alloc((size_t)e * 4);
    (void)ws_size; (void)n_in; (void)out_size;

    hipMemsetAsync(deg, 0, (size_t)n * 4, stream);
    hipMemsetAsync(cur, 0, (size_t)n * 4, stream);

    const int NB = (n + 1023) / 1024;    // 98 scan blocks

    count_kernel<<<(e + 255) / 256, 256, 0, stream>>>(src, dst, deg, e);
    encoder_kernel<<<n / 8, 256, 0, stream>>>(ef, Wq, bq, Wk, bk, Wv, bv, g0, be0,
                                              Wf1, bf1, Wf2, bf2, g1, be1, Wrep, brep,
                                              xt, n);
    xw1_kernel<<<n / 16, 256, 0, stream>>>(x, W1, att1, xw1b, ai1, n);
    scan1_kernel<<<NB, 1024, 0, stream>>>(deg, bsum, n);
    scan2_kernel<<<1, 128, 0, stream>>>(bsum, NB);
    scan3_kernel<<<NB, 1024, 0, stream>>>(deg, bsum, offs, n);
    scatter_kernel<<<(e + 255) / 256, 256, 0, stream>>>(src, dst, offs, cur, elist, e);
    agg1_kernel<<<n / 4, 256, 0, stream>>>(xw1b, ai1, att1, b1,
                                           offs, deg, elist, h1b, n);
    xw2pack_kernel<<<n / 16, 256, 0, stream>>>(h1b, xt, W2, att2, xw2p, ai2, n);
    agg2_kernel<<<n / 4, 256, 0, stream>>>((const unsigned*)xw2p, ai2, b2,
                                           offs, deg, elist, (float*)d_out, n);
}

// Round 11
// 772.429 us; speedup vs baseline: 3.6162x; 3.6162x over previous
//
#include <hip/hip_runtime.h>
#include <hip/hip_bf16.h>

// N=100000, E=1600000.
// R11: R10 encoder (bf16 K/V slab + streaming FFN) with NATURAL register
// budget (no forced min-waves -> R10's 7.9GB scratch-spill disaster undone).

#define NEG_SLOPE 0.2f

__device__ __forceinline__ float bf_lo(unsigned u) { return __uint_as_float(u << 16); }
__device__ __forceinline__ float bf_hi(unsigned u) { return __uint_as_float(u & 0xffff0000u); }
__device__ __forceinline__ unsigned pk(float lo, float hi)
{
    __hip_bfloat16 l = __float2bfloat16(lo), h = __float2bfloat16(hi);
    unsigned ul = reinterpret_cast<unsigned short&>(l);
    unsigned uh = reinterpret_cast<unsigned short&>(h);
    return ul | (uh << 16);
}

// ---------------------------------------------------------------------------
// Encoder: 8 nodes/block, 32 lanes/node. K/V staged as bf16 (32B/token).
// ---------------------------------------------------------------------------
__global__ void __launch_bounds__(256) encoder_kernel(
    const float* __restrict__ Xf,
    const float* __restrict__ Wq, const float* __restrict__ bq,
    const float* __restrict__ Wk, const float* __restrict__ bk,
    const float* __restrict__ Wv, const float* __restrict__ bv,
    const float* __restrict__ g0, const float* __restrict__ be0,
    const float* __restrict__ Wf1, const float* __restrict__ bf1,
    const float* __restrict__ Wf2, const float* __restrict__ bf2,
    const float* __restrict__ g1, const float* __restrict__ be1,
    const float* __restrict__ Wrep, const float* __restrict__ brep,
    float* __restrict__ xt, int n)
{
    __shared__ float sh[2560];
    int t = threadIdx.x;
    int bid = blockIdx.x;
    size_t base = (size_t)bid * 2560;
#pragma unroll
    for (int i = 0; i < 10; ++i) sh[i * 256 + t] = Xf[base + i * 256 + t];
    __syncthreads();

    int sub = t >> 5;
    int s   = t & 31;
    int v   = bid * 8 + sub;

    float xv[10];
#pragma unroll
    for (int i = 0; i < 10; ++i) xv[i] = sh[sub * 320 + s * 10 + i];
    __syncthreads();   // Xf consumed; slab reused for bf16 K/V

    float q[6], k[6], w[6];
#pragma unroll
    for (int j = 0; j < 6; ++j) { q[j] = bq[j]; k[j] = bk[j]; w[j] = bv[j]; }
#pragma unroll
    for (int i = 0; i < 10; ++i) {
#pragma unroll
        for (int j = 0; j < 6; ++j) {
            q[j] += xv[i] * Wq[i * 6 + j];
            k[j] += xv[i] * Wk[i * 6 + j];
            w[j] += xv[i] * Wv[i * 6 + j];
        }
    }

    // K/V slab: per node 32 tokens x 2 uint4 (k01,k23,k45,v01 | v23,v45,-,-).
    // Same-wave producer/consumer only.
    uint4* shu = (uint4*)sh;
    int nb = sub * 64;                       // node base in uint4 units
    shu[nb + s * 2]     = make_uint4(pk(k[0], k[1]), pk(k[2], k[3]),
                                     pk(k[4], k[5]), pk(w[0], w[1]));
    shu[nb + s * 2 + 1] = make_uint4(pk(w[2], w[3]), pk(w[4], w[5]), 0u, 0u);
    __builtin_amdgcn_wave_barrier();

    // logits |.| << 1 -> no max subtraction needed
    const float scale = 0.40824829046386301637f;  // 1/sqrt(6)
    float q0s = q[0] * scale, q1s = q[1] * scale, q2s = q[2] * scale;
    float q3s = q[3] * scale, q4s = q[4] * scale, q5s = q[5] * scale;

    float dA0 = 0.f, dB0 = 0.f, dA1 = 0.f, dB1 = 0.f;
    float aA00 = 0.f, aA01 = 0.f, aA02 = 0.f;
    float aB00 = 0.f, aB01 = 0.f, aB02 = 0.f;
    float aA10 = 0.f, aA11 = 0.f, aA12 = 0.f;
    float aB10 = 0.f, aB11 = 0.f, aB12 = 0.f;

#pragma unroll 4
    for (int t2 = 0; t2 < 32; t2 += 2) {
        uint4 Ua = shu[nb + t2 * 2];
        uint4 Ub = shu[nb + t2 * 2 + 1];
        uint4 Uc = shu[nb + t2 * 2 + 2];
        uint4 Ud = shu[nb + t2 * 2 + 3];
        // token t2
        {
            float k0 = bf_lo(Ua.x), k1 = bf_hi(Ua.x);
            float k2 = bf_lo(Ua.y), k3 = bf_hi(Ua.y);
            float k4 = bf_lo(Ua.z), k5 = bf_hi(Ua.z);
            float v0 = bf_lo(Ua.w), v1 = bf_hi(Ua.w);
            float v2 = bf_lo(Ub.x), v3 = bf_hi(Ub.x);
            float v4 = bf_lo(Ub.y), v5 = bf_hi(Ub.y);
            float p0 = __expf(q0s * k0 + q1s * k1 + q2s * k2);
            float p1 = __expf(q3s * k3 + q4s * k4 + q5s * k5);
            dA0 += p0; aA00 += p0 * v0; aA01 += p0 * v1; aA02 += p0 * v2;
            dA1 += p1; aA10 += p1 * v3; aA11 += p1 * v4; aA12 += p1 * v5;
        }
        // token t2+1
        {
            float k0 = bf_lo(Uc.x), k1 = bf_hi(Uc.x);
            float k2 = bf_lo(Uc.y), k3 = bf_hi(Uc.y);
            float k4 = bf_lo(Uc.z), k5 = bf_hi(Uc.z);
            float v0 = bf_lo(Uc.w), v1 = bf_hi(Uc.w);
            float v2 = bf_lo(Ud.x), v3 = bf_hi(Ud.x);
            float v4 = bf_lo(Ud.y), v5 = bf_hi(Ud.y);
            float p0 = __expf(q0s * k0 + q1s * k1 + q2s * k2);
            float p1 = __expf(q3s * k3 + q4s * k4 + q5s * k5);
            dB0 += p0; aB00 += p0 * v0; aB01 += p0 * v1; aB02 += p0 * v2;
            dB1 += p1; aB10 += p1 * v3; aB11 += p1 * v4; aB12 += p1 * v5;
        }
    }

    float O[6];
    {
        float inv0 = 1.f / (dA0 + dB0);
        float inv1 = 1.f / (dA1 + dB1);
        O[0] = q[0] + (aA00 + aB00) * inv0;
        O[1] = q[1] + (aA01 + aB01) * inv0;
        O[2] = q[2] + (aA02 + aB02) * inv0;
        O[3] = q[3] + (aA10 + aB10) * inv1;
        O[4] = q[4] + (aA11 + aB11) * inv1;
        O[5] = q[5] + (aA12 + aB12) * inv1;
    }

    // LayerNorm(g0, be0)
    {
        float mean = (O[0] + O[1] + O[2] + O[3] + O[4] + O[5]) * (1.f / 6.f);
        float var = 0.f;
#pragma unroll
        for (int j = 0; j < 6; ++j) { float d = O[j] - mean; var += d * d; }
        var *= (1.f / 6.f);
        float r = rsqrtf(var + 1e-5f);
#pragma unroll
        for (int j = 0; j < 6; ++j) O[j] = (O[j] - mean) * r * g0[j] + be0[j];
    }

    // streaming FFN 6->24->6 (no hidden buffer) + residual
    float f[6];
#pragma unroll
    for (int j = 0; j < 6; ++j) f[j] = O[j] + bf2[j];
#pragma unroll 4
    for (int r = 0; r < 24; ++r) {
        float hr = bf1[r];
#pragma unroll
        for (int j = 0; j < 6; ++j) hr += O[j] * Wf1[j * 24 + r];
        hr = fmaxf(hr, 0.f);
#pragma unroll
        for (int j = 0; j < 6; ++j) f[j] += hr * Wf2[r * 6 + j];
    }
    // LayerNorm(g1, be1)
    {
        float mean = (f[0] + f[1] + f[2] + f[3] + f[4] + f[5]) * (1.f / 6.f);
        float var = 0.f;
#pragma unroll
        for (int j = 0; j < 6; ++j) { float d = f[j] - mean; var += d * d; }
        var *= (1.f / 6.f);
        float r = rsqrtf(var + 1e-5f);
#pragma unroll
        for (int j = 0; j < 6; ++j) f[j] = (f[j] - mean) * r * g1[j] + be1[j];
    }

    float wr = Wrep[s];
#pragma unroll
    for (int j = 0; j < 6; ++j) {
        float val = f[j] * wr;
#pragma unroll
        for (int off = 16; off >= 1; off >>= 1) val += __shfl_xor(val, off, 32);
        f[j] = val;
    }
    if (s == 0) {
        float br = brep[0];
#pragma unroll
        for (int j = 0; j < 6; ++j) xt[(size_t)v * 6 + j] = f[j] + br;
    }
}

// ---------------------------------------------------------------------------
// xw1 = x @ W1 -> bf16 table (N,64); ai1 fp32 dots (N,8). 16 nodes/block.
// ---------------------------------------------------------------------------
__global__ void __launch_bounds__(256) xw1_kernel(
    const float* __restrict__ x, const float* __restrict__ W1,
    const float* __restrict__ att1,
    __hip_bfloat16* __restrict__ xwb,
    float* __restrict__ ai, int n)
{
    __shared__ float shW[4096];
    __shared__ float shX[256];
    int t = threadIdx.x, wv = t >> 6, l = t & 63;
#pragma unroll
    for (int i = 0; i < 16; ++i) shW[i * 256 + t] = W1[i * 256 + t];
    int h = l >> 3, c = l & 7;
    float a_i = att1[h * 16 + c];
    __syncthreads();

#pragma unroll
    for (int it = 0; it < 4; ++it) {
        int v = blockIdx.x * 16 + it * 4 + wv;
        shX[wv * 64 + l] = x[(size_t)v * 64 + l];
        __builtin_amdgcn_wave_barrier();
        float acc = 0.f;
#pragma unroll
        for (int k4 = 0; k4 < 16; ++k4) {
            float4 xb4 = *(const float4*)&shX[wv * 64 + k4 * 4];
            acc += xb4.x * shW[(k4 * 4 + 0) * 64 + l];
            acc += xb4.y * shW[(k4 * 4 + 1) * 64 + l];
            acc += xb4.z * shW[(k4 * 4 + 2) * 64 + l];
            acc += xb4.w * shW[(k4 * 4 + 3) * 64 + l];
        }
        xwb[(size_t)v * 64 + l] = __float2bfloat16(acc);

        float pi = acc * a_i;
#pragma unroll
        for (int off = 1; off < 8; off <<= 1)
            pi += __shfl_xor(pi, off, 64);
        if (c == 0) ai[(size_t)v * 8 + h] = pi;
        __builtin_amdgcn_wave_barrier();
    }
}

// ---------------------------------------------------------------------------
// CSR build: count -> 3-kernel scan -> scatter
// ---------------------------------------------------------------------------
__global__ void count_kernel(const int* __restrict__ src, const int* __restrict__ dst,
                             int* __restrict__ deg, int e)
{
    int i = blockIdx.x * blockDim.x + threadIdx.x;
    if (i < e) {
        int s = src[i], d = dst[i];
        if (s != d) atomicAdd(&deg[d], 1);
    }
}

__global__ void __launch_bounds__(1024) scan1_kernel(
    const int* __restrict__ deg, int* __restrict__ bsum, int n)
{
    __shared__ int sh[1024];
    int t = threadIdx.x;
    int i = blockIdx.x * 1024 + t;
    sh[t] = (i < n) ? deg[i] : 0;
    __syncthreads();
    for (int off = 512; off >= 1; off >>= 1) {
        if (t < off) sh[t] += sh[t + off];
        __syncthreads();
    }
    if (t == 0) bsum[blockIdx.x] = sh[0];
}

__global__ void __launch_bounds__(128) scan2_kernel(int* __restrict__ bsum, int nb)
{
    __shared__ int sh[128];
    int t = threadIdx.x;
    int v = (t < nb) ? bsum[t] : 0;
    sh[t] = v;
    __syncthreads();
    for (int off = 1; off < 128; off <<= 1) {
        int val = (t >= off) ? sh[t - off] : 0;
        __syncthreads();
        sh[t] += val;
        __syncthreads();
    }
    if (t < nb) bsum[t] = sh[t] - v;   // exclusive
}

__global__ void __launch_bounds__(1024) scan3_kernel(
    const int* __restrict__ deg, const int* __restrict__ bsum,
    int* __restrict__ offs, int n)
{
    __shared__ int sh[1024];
    int t = threadIdx.x;
    int i = blockIdx.x * 1024 + t;
    int v = (i < n) ? deg[i] : 0;
    sh[t] = v;
    __syncthreads();
    for (int off = 1; off < 1024; off <<= 1) {
        int val = (t >= off) ? sh[t - off] : 0;
        __syncthreads();
        sh[t] += val;
        __syncthreads();
    }
    if (i < n) offs[i] = bsum[blockIdx.x] + sh[t] - v;
}

__global__ void scatter_kernel(const int* __restrict__ src, const int* __restrict__ dst,
                               const int* __restrict__ offsets, int* __restrict__ cursor,
                               int* __restrict__ elist, int e)
{
    int i = blockIdx.x * blockDim.x + threadIdx.x;
    if (i < e) {
        int s = src[i], d = dst[i];
        if (s != d) {
            int pos = offsets[d] + atomicAdd(&cursor[d], 1);
            elist[pos] = s;
        }
    }
}

// ---------------------------------------------------------------------------
// PURE GAT-1 aggregation: ONE node per wave, ZERO LDS, no block barrier.
// Per edge: 1 row gather (128B line); aj1 recomputed via 3 shfl_xor.
// ---------------------------------------------------------------------------
__global__ void __launch_bounds__(256) agg1_kernel(
    const __hip_bfloat16* __restrict__ xwb, const float* __restrict__ ai1,
    const float* __restrict__ att1, const float* __restrict__ b1,
    const int* __restrict__ offs, const int* __restrict__ deg,
    const int* __restrict__ elist,
    __hip_bfloat16* __restrict__ h1b, int n)
{
    int t = threadIdx.x, wv = t >> 6, l = t & 63;
    int v = blockIdx.x * 4 + wv;
    int h = l >> 3, c = l & 7;
    float attj_l = att1[h * 16 + 8 + c];   // a_j[h][c]
    float ai_l = ai1[(size_t)v * 8 + h];

    float yself = __bfloat162float(xwb[(size_t)v * 64 + l]);
    float ps = yself * attj_l;
    ps += __shfl_xor(ps, 1, 64);
    ps += __shfl_xor(ps, 2, 64);
    ps += __shfl_xor(ps, 4, 64);
    float a = ai_l + ps;
    a = a >= 0.f ? a : NEG_SLOPE * a;
    float ea  = __expf(a);
    float acc = ea * yself;
    float den = ea;

    int off = offs[v], dg = deg[v];
    for (int j = 0; j < dg; j += 16) {
        int idxv = 0;
        if (l < 16 && j + l < dg) idxv = elist[off + j + l];
#pragma unroll
        for (int b = 0; b < 16; ++b) {
            int s = __shfl(idxv, b, 64);
            float y = __bfloat162float(xwb[(size_t)s * 64 + l]);
            float pp = y * attj_l;
            pp += __shfl_xor(pp, 1, 64);
            pp += __shfl_xor(pp, 2, 64);
            pp += __shfl_xor(pp, 4, 64);     // aj1[s][h] on all 8 lanes of head
            float aa = ai_l + pp;
            aa = aa >= 0.f ? aa : NEG_SLOPE * aa;
            float w = (j + b < dg) ? __expf(aa) : 0.f;  // scalar condition
            acc += w * y;
            den += w;
        }
    }

    float o = acc / den + b1[l];
    o = o > 0.f ? o : expm1f(o);   // elu
    h1b[(size_t)v * 64 + l] = __float2bfloat16(o);
}

// ---------------------------------------------------------------------------
// xw2pack: packed xw2 rows [80 bf16 | 8 bf16 aj2 | pad] stride 128 u16, + ai2.
// 16 nodes/block (4 per wave), W2 staged once per block.
// ---------------------------------------------------------------------------
__global__ void __launch_bounds__(256) xw2pack_kernel(
    const __hip_bfloat16* __restrict__ h1b, const float* __restrict__ xt,
    const float* __restrict__ W2, const float* __restrict__ att2,
    __hip_bfloat16* __restrict__ xw2p, float* __restrict__ ai2, int n)
{
    __shared__ float shW2[5600];
    __shared__ float shH[4][72];
    __shared__ float shR[4][80];
    int t = threadIdx.x, wv = t >> 6, l = t & 63;
    for (int i = t; i < 5600; i += 256) shW2[i] = W2[i];
    __syncthreads();

#pragma unroll
    for (int it = 0; it < 4; ++it) {
        int v = blockIdx.x * 16 + it * 4 + wv;

        shH[wv][l] = __bfloat162float(h1b[(size_t)v * 64 + l]);
        if (l < 6) shH[wv][64 + l] = xt[(size_t)v * 6 + l];
        __builtin_amdgcn_wave_barrier();

        float a0 = 0.f, a1 = 0.f;
#pragma unroll
        for (int kk = 0; kk < 70; ++kk) {
            float f = shH[wv][kk];
            a0 += f * shW2[kk * 80 + l];
            if (l < 16) a1 += f * shW2[kk * 80 + 64 + l];
        }
        __hip_bfloat16* row = xw2p + (size_t)v * 128;
        row[l] = __float2bfloat16(a0);
        shR[wv][l] = a0;
        if (l < 16) {
            row[64 + l] = __float2bfloat16(a1);
            shR[wv][64 + l] = a1;
        }
        __builtin_amdgcn_wave_barrier();

        if (l < 16) {
            int hh = l >> 1, wj = l & 1;
            float sdot = 0.f;
#pragma unroll
            for (int cc = 0; cc < 10; ++cc)
                sdot += shR[wv][hh * 10 + cc] * att2[hh * 20 + wj * 10 + cc];
            if (wj == 0) ai2[(size_t)v * 8 + hh] = sdot;
            else         row[80 + hh] = __float2bfloat16(sdot);  // aj2 packed
        }
        __builtin_amdgcn_wave_barrier();
    }
}

// ---------------------------------------------------------------------------
// GAT layer 2 aggregation on packed rows + head-mean + b2 + log_softmax.
// One node per wave; 1 u32 gather per edge (44 lanes) + 1 shfl.
// ---------------------------------------------------------------------------
__global__ void __launch_bounds__(256) agg2_kernel(
    const unsigned* __restrict__ xw2p, const float* __restrict__ ai2,
    const float* __restrict__ b2,
    const int* __restrict__ offs, const int* __restrict__ deg,
    const int* __restrict__ elist, float* __restrict__ out, int n)
{
    __shared__ float buf[4][80];
    __shared__ float buf2[4][10];
    int t = threadIdx.x, wv = t >> 6, l = t & 63;
    int v = blockIdx.x * 4 + wv;

    bool act = l < 44;
    int hc = (l < 40) ? (l / 5) : 0;       // head of cols (2l, 2l+1)
    int ajl = 40 + (hc >> 1);              // holder lane of aj pair
    float ai_l = (l < 40) ? ai2[(size_t)v * 8 + hc] : 0.f;

    unsigned selfw = 0;
    if (act) selfw = xw2p[(size_t)v * 64 + l];
    unsigned ajw = __shfl(selfw, ajl, 64);
    float ajs = (hc & 1) ? bf_hi(ajw) : bf_lo(ajw);
    float a = ai_l + ajs;
    a = a >= 0.f ? a : NEG_SLOPE * a;
    float e0 = __expf(a);
    float acc0 = e0 * bf_lo(selfw), acc1 = e0 * bf_hi(selfw), den = e0;

    int off = offs[v], dg = deg[v];
    for (int j = 0; j < dg; j += 16) {
        int idxv = 0;
        if (l < 16 && j + l < dg) idxv = elist[off + j + l];
#pragma unroll
        for (int b = 0; b < 16; ++b) {
            int s = __shfl(idxv, b, 64);
            unsigned yw = 0;
            if (act) yw = xw2p[(size_t)s * 64 + l];
            unsigned aw = __shfl(yw, ajl, 64);
            float aj = (hc & 1) ? bf_hi(aw) : bf_lo(aw);
            float u = ai_l + aj;
            u = u >= 0.f ? u : NEG_SLOPE * u;
            float w = (j + b < dg) ? __expf(u) : 0.f;   // scalar condition
            acc0 += w * bf_lo(yw);
            acc1 += w * bf_hi(yw);
            den += w;
        }
    }

    if (l < 40) {
        float inv = 1.f / den;
        buf[wv][2 * l]     = acc0 * inv;
        buf[wv][2 * l + 1] = acc1 * inv;
    }
    __builtin_amdgcn_wave_barrier();
    if (l < 10) {
        float mval = 0.f;
#pragma unroll
        for (int hh = 0; hh < 8; ++hh) mval += buf[wv][hh * 10 + l];
        buf2[wv][l] = mval * 0.125f + b2[l];
    }
    __builtin_amdgcn_wave_barrier();
    if (l < 10) {
        float mx = -1e30f;
#pragma unroll
        for (int cc = 0; cc < 10; ++cc) mx = fmaxf(mx, buf2[wv][cc]);
        float se = 0.f;
#pragma unroll
        for (int cc = 0; cc < 10; ++cc) se += __expf(buf2[wv][cc] - mx);
        out[(size_t)v * 10 + l] = buf2[wv][l] - mx - __logf(se);
    }
}

// ---------------------------------------------------------------------------
extern "C" void kernel_launch(void* const* d_in, const int* in_sizes, int n_in,
                              void* d_out, int out_size, void* d_ws, size_t ws_size,
                              hipStream_t stream)
{
    const float* x    = (const float*)d_in[0];
    const int*   ei   = (const int*)  d_in[1];
    const float* ef   = (const float*)d_in[2];
    const float* W1   = (const float*)d_in[3];
    const float* att1 = (const float*)d_in[4];
    const float* b1   = (const float*)d_in[5];
    const float* W2   = (const float*)d_in[6];
    const float* att2 = (const float*)d_in[7];
    const float* b2   = (const float*)d_in[8];
    const float* Wq   = (const float*)d_in[9];
    const float* bq   = (const float*)d_in[10];
    const float* Wk   = (const float*)d_in[11];
    const float* bk   = (const float*)d_in[12];
    const float* Wv   = (const float*)d_in[13];
    const float* bv   = (const float*)d_in[14];
    const float* g0   = (const float*)d_in[15];
    const float* be0  = (const float*)d_in[16];
    const float* Wf1  = (const float*)d_in[17];
    const float* bf1  = (const float*)d_in[18];
    const float* Wf2  = (const float*)d_in[19];
    const float* bf2  = (const float*)d_in[20];
    const float* g1   = (const float*)d_in[21];
    const float* be1  = (const float*)d_in[22];
    const float* Wrep = (const float*)d_in[23];
    const float* brep = (const float*)d_in[24];

    const int n = in_sizes[0] / 64;   // 100000
    const int e = in_sizes[1] / 2;    // 1600000
    const int* src = ei;
    const int* dst = ei + e;

    char* ws = (char*)d_ws;
    size_t o = 0;
    auto alloc = [&](size_t bytes) -> void* {
        void* p = ws + o;
        o += (bytes + 255) & ~(size_t)255;
        return p;
    };
    __hip_bfloat16* xw1b = (__hip_bfloat16*)alloc((size_t)n * 64 * 2);
    __hip_bfloat16* h1b  = (__hip_bfloat16*)alloc((size_t)n * 64 * 2);
    __hip_bfloat16* xw2p = (__hip_bfloat16*)alloc((size_t)n * 128 * 2); // packed
    float* ai1   = (float*)alloc((size_t)n * 8 * 4);
    float* ai2   = (float*)alloc((size_t)n * 8 * 4);
    float* xt    = (float*)alloc((size_t)n * 6 * 4);
    int*   deg   = (int*)  alloc((size_t)n * 4);
    int*   offs  = (int*)  alloc((size_t)n * 4);
    int*   cur   = (int*)  alloc((size_t)n * 4);
    int*   bsum  = (int*)  alloc(256 * 4);
    int*   elist = (int*)  alloc((size_t)e * 4);
    (void)ws_size; (void)n_in; (void)out_size;

    hipMemsetAsync(deg, 0, (size_t)n * 4, stream);
    hipMemsetAsync(cur, 0, (size_t)n * 4, stream);

    const int NB = (n + 1023) / 1024;    // 98 scan blocks

    count_kernel<<<(e + 255) / 256, 256, 0, stream>>>(src, dst, deg, e);
    encoder_kernel<<<n / 8, 256, 0, stream>>>(ef, Wq, bq, Wk, bk, Wv, bv, g0, be0,
                                              Wf1, bf1, Wf2, bf2, g1, be1, Wrep, brep,
                                              xt, n);
    xw1_kernel<<<n / 16, 256, 0, stream>>>(x, W1, att1, xw1b, ai1, n);
    scan1_kernel<<<NB, 1024, 0, stream>>>(deg, bsum, n);
    scan2_kernel<<<1, 128, 0, stream>>>(bsum, NB);
    scan3_kernel<<<NB, 1024, 0, stream>>>(deg, bsum, offs, n);
    scatter_kernel<<<(e + 255) / 256, 256, 0, stream>>>(src, dst, offs, cur, elist, e);
    agg1_kernel<<<n / 4, 256, 0, stream>>>(xw1b, ai1, att1, b1,
                                           offs, deg, elist, h1b, n);
    xw2pack_kernel<<<n / 16, 256, 0, stream>>>(h1b, xt, W2, att2, xw2p, ai2, n);
    agg2_kernel<<<n / 4, 256, 0, stream>>>((const unsigned*)xw2p, ai2, b2,
                                           offs, deg, elist, (float*)d_out, n);
}

// Round 12
// 645.033 us; speedup vs baseline: 4.3305x; 1.1975x over previous
//
#include <hip/hip_runtime.h>
#include <hip/hip_bf16.h>

// N=100000, E=1600000.
// R12: agg kernels restructured as 8-edge chunks with a phase-1 "weight
// batch" (full wave computes w[e][h] for 8 edges x 8 heads in one pass)
// + lean phase-2 (gather + 1 bpermute + fma per edge). Cuts wave-issue
// instructions per edge ~2x. aj1 precomputed packed-bf16 by xw1.

#define NEG_SLOPE 0.2f

__device__ __forceinline__ float bf_lo(unsigned u) { return __uint_as_float(u << 16); }
__device__ __forceinline__ float bf_hi(unsigned u) { return __uint_as_float(u & 0xffff0000u); }
__device__ __forceinline__ unsigned pk(float lo, float hi)
{
    __hip_bfloat16 l = __float2bfloat16(lo), h = __float2bfloat16(hi);
    unsigned ul = reinterpret_cast<unsigned short&>(l);
    unsigned uh = reinterpret_cast<unsigned short&>(h);
    return ul | (uh << 16);
}

// ---------------------------------------------------------------------------
// Encoder: 8 nodes/block, 32 lanes/node. K/V staged as bf16 (32B/token).
// ---------------------------------------------------------------------------
__global__ void __launch_bounds__(256) encoder_kernel(
    const float* __restrict__ Xf,
    const float* __restrict__ Wq, const float* __restrict__ bq,
    const float* __restrict__ Wk, const float* __restrict__ bk,
    const float* __restrict__ Wv, const float* __restrict__ bv,
    const float* __restrict__ g0, const float* __restrict__ be0,
    const float* __restrict__ Wf1, const float* __restrict__ bf1,
    const float* __restrict__ Wf2, const float* __restrict__ bf2,
    const float* __restrict__ g1, const float* __restrict__ be1,
    const float* __restrict__ Wrep, const float* __restrict__ brep,
    float* __restrict__ xt, int n)
{
    __shared__ float sh[2560];
    int t = threadIdx.x;
    int bid = blockIdx.x;
    size_t base = (size_t)bid * 2560;
#pragma unroll
    for (int i = 0; i < 10; ++i) sh[i * 256 + t] = Xf[base + i * 256 + t];
    __syncthreads();

    int sub = t >> 5;
    int s   = t & 31;
    int v   = bid * 8 + sub;

    float xv[10];
#pragma unroll
    for (int i = 0; i < 10; ++i) xv[i] = sh[sub * 320 + s * 10 + i];
    __syncthreads();   // Xf consumed; slab reused for bf16 K/V

    float q[6], k[6], w[6];
#pragma unroll
    for (int j = 0; j < 6; ++j) { q[j] = bq[j]; k[j] = bk[j]; w[j] = bv[j]; }
#pragma unroll
    for (int i = 0; i < 10; ++i) {
#pragma unroll
        for (int j = 0; j < 6; ++j) {
            q[j] += xv[i] * Wq[i * 6 + j];
            k[j] += xv[i] * Wk[i * 6 + j];
            w[j] += xv[i] * Wv[i * 6 + j];
        }
    }

    uint4* shu = (uint4*)sh;
    int nb = sub * 64;
    shu[nb + s * 2]     = make_uint4(pk(k[0], k[1]), pk(k[2], k[3]),
                                     pk(k[4], k[5]), pk(w[0], w[1]));
    shu[nb + s * 2 + 1] = make_uint4(pk(w[2], w[3]), pk(w[4], w[5]), 0u, 0u);
    __builtin_amdgcn_wave_barrier();

    const float scale = 0.40824829046386301637f;  // 1/sqrt(6)
    float q0s = q[0] * scale, q1s = q[1] * scale, q2s = q[2] * scale;
    float q3s = q[3] * scale, q4s = q[4] * scale, q5s = q[5] * scale;

    float dA0 = 0.f, dB0 = 0.f, dA1 = 0.f, dB1 = 0.f;
    float aA00 = 0.f, aA01 = 0.f, aA02 = 0.f;
    float aB00 = 0.f, aB01 = 0.f, aB02 = 0.f;
    float aA10 = 0.f, aA11 = 0.f, aA12 = 0.f;
    float aB10 = 0.f, aB11 = 0.f, aB12 = 0.f;

#pragma unroll 4
    for (int t2 = 0; t2 < 32; t2 += 2) {
        uint4 Ua = shu[nb + t2 * 2];
        uint4 Ub = shu[nb + t2 * 2 + 1];
        uint4 Uc = shu[nb + t2 * 2 + 2];
        uint4 Ud = shu[nb + t2 * 2 + 3];
        {
            float k0 = bf_lo(Ua.x), k1 = bf_hi(Ua.x);
            float k2 = bf_lo(Ua.y), k3 = bf_hi(Ua.y);
            float k4 = bf_lo(Ua.z), k5 = bf_hi(Ua.z);
            float v0 = bf_lo(Ua.w), v1 = bf_hi(Ua.w);
            float v2 = bf_lo(Ub.x), v3 = bf_hi(Ub.x);
            float v4 = bf_lo(Ub.y), v5 = bf_hi(Ub.y);
            float p0 = __expf(q0s * k0 + q1s * k1 + q2s * k2);
            float p1 = __expf(q3s * k3 + q4s * k4 + q5s * k5);
            dA0 += p0; aA00 += p0 * v0; aA01 += p0 * v1; aA02 += p0 * v2;
            dA1 += p1; aA10 += p1 * v3; aA11 += p1 * v4; aA12 += p1 * v5;
        }
        {
            float k0 = bf_lo(Uc.x), k1 = bf_hi(Uc.x);
            float k2 = bf_lo(Uc.y), k3 = bf_hi(Uc.y);
            float k4 = bf_lo(Uc.z), k5 = bf_hi(Uc.z);
            float v0 = bf_lo(Uc.w), v1 = bf_hi(Uc.w);
            float v2 = bf_lo(Ud.x), v3 = bf_hi(Ud.x);
            float v4 = bf_lo(Ud.y), v5 = bf_hi(Ud.y);
            float p0 = __expf(q0s * k0 + q1s * k1 + q2s * k2);
            float p1 = __expf(q3s * k3 + q4s * k4 + q5s * k5);
            dB0 += p0; aB00 += p0 * v0; aB01 += p0 * v1; aB02 += p0 * v2;
            dB1 += p1; aB10 += p1 * v3; aB11 += p1 * v4; aB12 += p1 * v5;
        }
    }

    float O[6];
    {
        float inv0 = 1.f / (dA0 + dB0);
        float inv1 = 1.f / (dA1 + dB1);
        O[0] = q[0] + (aA00 + aB00) * inv0;
        O[1] = q[1] + (aA01 + aB01) * inv0;
        O[2] = q[2] + (aA02 + aB02) * inv0;
        O[3] = q[3] + (aA10 + aB10) * inv1;
        O[4] = q[4] + (aA11 + aB11) * inv1;
        O[5] = q[5] + (aA12 + aB12) * inv1;
    }

    {
        float mean = (O[0] + O[1] + O[2] + O[3] + O[4] + O[5]) * (1.f / 6.f);
        float var = 0.f;
#pragma unroll
        for (int j = 0; j < 6; ++j) { float d = O[j] - mean; var += d * d; }
        var *= (1.f / 6.f);
        float r = rsqrtf(var + 1e-5f);
#pragma unroll
        for (int j = 0; j < 6; ++j) O[j] = (O[j] - mean) * r * g0[j] + be0[j];
    }

    float f[6];
#pragma unroll
    for (int j = 0; j < 6; ++j) f[j] = O[j] + bf2[j];
#pragma unroll 4
    for (int r = 0; r < 24; ++r) {
        float hr = bf1[r];
#pragma unroll
        for (int j = 0; j < 6; ++j) hr += O[j] * Wf1[j * 24 + r];
        hr = fmaxf(hr, 0.f);
#pragma unroll
        for (int j = 0; j < 6; ++j) f[j] += hr * Wf2[r * 6 + j];
    }
    {
        float mean = (f[0] + f[1] + f[2] + f[3] + f[4] + f[5]) * (1.f / 6.f);
        float var = 0.f;
#pragma unroll
        for (int j = 0; j < 6; ++j) { float d = f[j] - mean; var += d * d; }
        var *= (1.f / 6.f);
        float r = rsqrtf(var + 1e-5f);
#pragma unroll
        for (int j = 0; j < 6; ++j) f[j] = (f[j] - mean) * r * g1[j] + be1[j];
    }

    float wr = Wrep[s];
#pragma unroll
    for (int j = 0; j < 6; ++j) {
        float val = f[j] * wr;
#pragma unroll
        for (int off = 16; off >= 1; off >>= 1) val += __shfl_xor(val, off, 32);
        f[j] = val;
    }
    if (s == 0) {
        float br = brep[0];
#pragma unroll
        for (int j = 0; j < 6; ++j) xt[(size_t)v * 6 + j] = f[j] + br;
    }
}

// ---------------------------------------------------------------------------
// xw1 = x @ W1 -> bf16 table (N,64); ai1 fp32 (N,8); aj1 packed bf16 (N,4 u32).
// ---------------------------------------------------------------------------
__global__ void __launch_bounds__(256) xw1_kernel(
    const float* __restrict__ x, const float* __restrict__ W1,
    const float* __restrict__ att1,
    __hip_bfloat16* __restrict__ xwb,
    float* __restrict__ ai, unsigned* __restrict__ ajp, int n)
{
    __shared__ float shW[4096];
    __shared__ float shX[256];
    int t = threadIdx.x, wv = t >> 6, l = t & 63;
#pragma unroll
    for (int i = 0; i < 16; ++i) shW[i * 256 + t] = W1[i * 256 + t];
    int h = l >> 3, c = l & 7;
    float a_i = att1[h * 16 + c];
    float a_j = att1[h * 16 + 8 + c];
    __syncthreads();

#pragma unroll
    for (int it = 0; it < 4; ++it) {
        int v = blockIdx.x * 16 + it * 4 + wv;
        shX[wv * 64 + l] = x[(size_t)v * 64 + l];
        __builtin_amdgcn_wave_barrier();
        float acc = 0.f;
#pragma unroll
        for (int k4 = 0; k4 < 16; ++k4) {
            float4 xb4 = *(const float4*)&shX[wv * 64 + k4 * 4];
            acc += xb4.x * shW[(k4 * 4 + 0) * 64 + l];
            acc += xb4.y * shW[(k4 * 4 + 1) * 64 + l];
            acc += xb4.z * shW[(k4 * 4 + 2) * 64 + l];
            acc += xb4.w * shW[(k4 * 4 + 3) * 64 + l];
        }
        xwb[(size_t)v * 64 + l] = __float2bfloat16(acc);

        float pi = acc * a_i;
        float pj = acc * a_j;
#pragma unroll
        for (int off = 1; off < 8; off <<= 1) {
            pi += __shfl_xor(pi, off, 64);
            pj += __shfl_xor(pj, off, 64);
        }
        if (c == 0) ai[(size_t)v * 8 + h] = pi;
        float pj_hi = __shfl(pj, (l + 8) & 63, 64);
        if ((l & 15) == 0)
            ajp[(size_t)v * 4 + (h >> 1)] = pk(pj, pj_hi);
        __builtin_amdgcn_wave_barrier();
    }
}

// ---------------------------------------------------------------------------
// CSR build: count -> 3-kernel scan -> scatter
// ---------------------------------------------------------------------------
__global__ void count_kernel(const int* __restrict__ src, const int* __restrict__ dst,
                             int* __restrict__ deg, int e)
{
    int i = blockIdx.x * blockDim.x + threadIdx.x;
    if (i < e) {
        int s = src[i], d = dst[i];
        if (s != d) atomicAdd(&deg[d], 1);
    }
}

__global__ void __launch_bounds__(1024) scan1_kernel(
    const int* __restrict__ deg, int* __restrict__ bsum, int n)
{
    __shared__ int sh[1024];
    int t = threadIdx.x;
    int i = blockIdx.x * 1024 + t;
    sh[t] = (i < n) ? deg[i] : 0;
    __syncthreads();
    for (int off = 512; off >= 1; off >>= 1) {
        if (t < off) sh[t] += sh[t + off];
        __syncthreads();
    }
    if (t == 0) bsum[blockIdx.x] = sh[0];
}

__global__ void __launch_bounds__(128) scan2_kernel(int* __restrict__ bsum, int nb)
{
    __shared__ int sh[128];
    int t = threadIdx.x;
    int v = (t < nb) ? bsum[t] : 0;
    sh[t] = v;
    __syncthreads();
    for (int off = 1; off < 128; off <<= 1) {
        int val = (t >= off) ? sh[t - off] : 0;
        __syncthreads();
        sh[t] += val;
        __syncthreads();
    }
    if (t < nb) bsum[t] = sh[t] - v;   // exclusive
}

__global__ void __launch_bounds__(1024) scan3_kernel(
    const int* __restrict__ deg, const int* __restrict__ bsum,
    int* __restrict__ offs, int n)
{
    __shared__ int sh[1024];
    int t = threadIdx.x;
    int i = blockIdx.x * 1024 + t;
    int v = (i < n) ? deg[i] : 0;
    sh[t] = v;
    __syncthreads();
    for (int off = 1; off < 1024; off <<= 1) {
        int val = (t >= off) ? sh[t - off] : 0;
        __syncthreads();
        sh[t] += val;
        __syncthreads();
    }
    if (i < n) offs[i] = bsum[blockIdx.x] + sh[t] - v;
}

__global__ void scatter_kernel(const int* __restrict__ src, const int* __restrict__ dst,
                               const int* __restrict__ offsets, int* __restrict__ cursor,
                               int* __restrict__ elist, int e)
{
    int i = blockIdx.x * blockDim.x + threadIdx.x;
    if (i < e) {
        int s = src[i], d = dst[i];
        if (s != d) {
            int pos = offsets[d] + atomicAdd(&cursor[d], 1);
            elist[pos] = s;
        }
    }
}

// ---------------------------------------------------------------------------
// GAT-1 aggregation, 8-edge chunks, two-phase:
//   phase 1: lane (e=l>>3, h=l&7) computes w[e][h] from packed aj table
//   phase 2: per edge: row gather + 1 bpermute(w) + fma
// den accumulated in phase-1 layout; reduced once per node.
// ---------------------------------------------------------------------------
__global__ void __launch_bounds__(256) agg1_kernel(
    const __hip_bfloat16* __restrict__ xwb, const float* __restrict__ ai1,
    const unsigned* __restrict__ ajp, const float* __restrict__ att1,
    const float* __restrict__ b1,
    const int* __restrict__ offs, const int* __restrict__ deg,
    const int* __restrict__ elist,
    __hip_bfloat16* __restrict__ h1b, int n)
{
    int t = threadIdx.x, wv = t >> 6, l = t & 63;
    int v = blockIdx.x * 4 + wv;
    int h = l >> 3, c = l & 7;    // output layout: lane = col l, head h
    int e1 = l >> 3, hp = l & 7;  // phase-1 layout: (edge slot e1, head hp)

    float ai_l = ai1[(size_t)v * 8 + h];    // == phase-1's ai for head hp? no:
    float ai_p = ai1[(size_t)v * 8 + hp];   // separate value per layout
    float attj_l = att1[h * 16 + 8 + c];

    // self loop (output layout; butterfly over own row)
    float yself = __bfloat162float(xwb[(size_t)v * 64 + l]);
    float ps = yself * attj_l;
    ps += __shfl_xor(ps, 1, 64);
    ps += __shfl_xor(ps, 2, 64);
    ps += __shfl_xor(ps, 4, 64);
    float a = ai_l + ps;
    a = fmaxf(a, NEG_SLOPE * a);
    float ea  = __expf(a);
    float acc = ea * yself;

    float den_acc = 0.f;   // phase-1 layout
    int off = offs[v], dg = deg[v];
    for (int j = 0; j < dg; j += 8) {
        int idxv = 0;
        if (l < 8 && j + l < dg) idxv = elist[off + j + l];
        // phase 1: weights for 8 edges x 8 heads
        int se = __shfl(idxv, e1, 64);
        unsigned aw = ajp[(size_t)se * 4 + (hp >> 1)];
        float ajv = (hp & 1) ? bf_hi(aw) : bf_lo(aw);
        float u = ai_p + ajv;
        u = fmaxf(u, NEG_SLOPE * u);
        float wl = __expf(u);
        wl = (j + e1 < dg) ? wl : 0.f;
        den_acc += wl;
        // phase 2: gather + apply
#pragma unroll
        for (int b = 0; b < 8; ++b) {
            int s = __shfl(idxv, b, 64);
            float y = __bfloat162float(xwb[(size_t)s * 64 + l]);
            float w = __shfl(wl, b * 8 + h, 64);
            acc += w * y;
        }
    }
    den_acc += __shfl_xor(den_acc, 8, 64);
    den_acc += __shfl_xor(den_acc, 16, 64);
    den_acc += __shfl_xor(den_acc, 32, 64);
    float den = ea + __shfl(den_acc, h, 64);

    float o = acc / den + b1[l];
    o = o > 0.f ? o : expm1f(o);   // elu
    h1b[(size_t)v * 64 + l] = __float2bfloat16(o);
}

// ---------------------------------------------------------------------------
// xw2pack: packed xw2 rows [80 bf16 | 8 bf16 aj2 | pad] stride 128 u16, + ai2.
// ---------------------------------------------------------------------------
__global__ void __launch_bounds__(256) xw2pack_kernel(
    const __hip_bfloat16* __restrict__ h1b, const float* __restrict__ xt,
    const float* __restrict__ W2, const float* __restrict__ att2,
    __hip_bfloat16* __restrict__ xw2p, float* __restrict__ ai2, int n)
{
    __shared__ float shW2[5600];
    __shared__ float shH[4][72];
    __shared__ float shR[4][80];
    int t = threadIdx.x, wv = t >> 6, l = t & 63;
    for (int i = t; i < 5600; i += 256) shW2[i] = W2[i];
    __syncthreads();

#pragma unroll
    for (int it = 0; it < 4; ++it) {
        int v = blockIdx.x * 16 + it * 4 + wv;

        shH[wv][l] = __bfloat162float(h1b[(size_t)v * 64 + l]);
        if (l < 6) shH[wv][64 + l] = xt[(size_t)v * 6 + l];
        __builtin_amdgcn_wave_barrier();

        float a0 = 0.f, a1 = 0.f;
#pragma unroll
        for (int kk = 0; kk < 70; ++kk) {
            float f = shH[wv][kk];
            a0 += f * shW2[kk * 80 + l];
            if (l < 16) a1 += f * shW2[kk * 80 + 64 + l];
        }
        __hip_bfloat16* row = xw2p + (size_t)v * 128;
        row[l] = __float2bfloat16(a0);
        shR[wv][l] = a0;
        if (l < 16) {
            row[64 + l] = __float2bfloat16(a1);
            shR[wv][64 + l] = a1;
        }
        __builtin_amdgcn_wave_barrier();

        if (l < 16) {
            int hh = l >> 1, wj = l & 1;
            float sdot = 0.f;
#pragma unroll
            for (int cc = 0; cc < 10; ++cc)
                sdot += shR[wv][hh * 10 + cc] * att2[hh * 20 + wj * 10 + cc];
            if (wj == 0) ai2[(size_t)v * 8 + hh] = sdot;
            else         row[80 + hh] = __float2bfloat16(sdot);  // aj2 packed
        }
        __builtin_amdgcn_wave_barrier();
    }
}

// ---------------------------------------------------------------------------
// GAT-2 aggregation on packed rows, 8-edge chunks, two-phase (as agg1).
// Lane l<40: cols 2l,2l+1 (head hc=l/5). aj2 words sit at u32 index 40..43.
// ---------------------------------------------------------------------------
__global__ void __launch_bounds__(256) agg2_kernel(
    const unsigned* __restrict__ xw2p, const float* __restrict__ ai2,
    const float* __restrict__ b2,
    const int* __restrict__ offs, const int* __restrict__ deg,
    const int* __restrict__ elist, float* __restrict__ out, int n)
{
    __shared__ float buf[4][80];
    __shared__ float buf2[4][10];
    int t = threadIdx.x, wv = t >> 6, l = t & 63;
    int v = blockIdx.x * 4 + wv;

    int hc = (l < 40) ? (l / 5) : 0;
    int e1 = l >> 3, hp = l & 7;
    float ai_p = ai2[(size_t)v * 8 + hp];
    float ai_l = (l < 40) ? ai2[(size_t)v * 8 + hc] : 0.f;

    // self loop
    bool act = l < 44;
    unsigned selfw = act ? xw2p[(size_t)v * 64 + l] : 0u;
    int ajl = 40 + (hc >> 1);
    unsigned ajw = __shfl(selfw, ajl, 64);
    float ajs = (hc & 1) ? bf_hi(ajw) : bf_lo(ajw);
    float a = ai_l + ajs;
    a = fmaxf(a, NEG_SLOPE * a);
    float e0 = __expf(a);
    float acc0 = e0 * bf_lo(selfw), acc1 = e0 * bf_hi(selfw);

    float den_acc = 0.f;   // phase-1 layout
    int off = offs[v], dg = deg[v];
    for (int j = 0; j < dg; j += 8) {
        int idxv = 0;
        if (l < 8 && j + l < dg) idxv = elist[off + j + l];
        // phase 1: weights for 8 edges x 8 heads (aj words in-row at 40+h/2)
        int se = __shfl(idxv, e1, 64);
        unsigned aw = xw2p[(size_t)se * 64 + 40 + (hp >> 1)];
        float ajv = (hp & 1) ? bf_hi(aw) : bf_lo(aw);
        float u = ai_p + ajv;
        u = fmaxf(u, NEG_SLOPE * u);
        float wl = __expf(u);
        wl = (j + e1 < dg) ? wl : 0.f;
        den_acc += wl;
        // phase 2
#pragma unroll
        for (int b = 0; b < 8; ++b) {
            int s = __shfl(idxv, b, 64);
            unsigned yw = (l < 40) ? xw2p[(size_t)s * 64 + l] : 0u;
            float w = __shfl(wl, b * 8 + hc, 64);
            acc0 += w * bf_lo(yw);
            acc1 += w * bf_hi(yw);
        }
    }
    den_acc += __shfl_xor(den_acc, 8, 64);
    den_acc += __shfl_xor(den_acc, 16, 64);
    den_acc += __shfl_xor(den_acc, 32, 64);
    float den = e0 + __shfl(den_acc, hc, 64);

    if (l < 40) {
        float inv = 1.f / den;
        buf[wv][2 * l]     = acc0 * inv;
        buf[wv][2 * l + 1] = acc1 * inv;
    }
    __builtin_amdgcn_wave_barrier();
    if (l < 10) {
        float mval = 0.f;
#pragma unroll
        for (int hh = 0; hh < 8; ++hh) mval += buf[wv][hh * 10 + l];
        buf2[wv][l] = mval * 0.125f + b2[l];
    }
    __builtin_amdgcn_wave_barrier();
    if (l < 10) {
        float mx = -1e30f;
#pragma unroll
        for (int cc = 0; cc < 10; ++cc) mx = fmaxf(mx, buf2[wv][cc]);
        float se = 0.f;
#pragma unroll
        for (int cc = 0; cc < 10; ++cc) se += __expf(buf2[wv][cc] - mx);
        out[(size_t)v * 10 + l] = buf2[wv][l] - mx - __logf(se);
    }
}

// ---------------------------------------------------------------------------
extern "C" void kernel_launch(void* const* d_in, const int* in_sizes, int n_in,
                              void* d_out, int out_size, void* d_ws, size_t ws_size,
                              hipStream_t stream)
{
    const float* x    = (const float*)d_in[0];
    const int*   ei   = (const int*)  d_in[1];
    const float* ef   = (const float*)d_in[2];
    const float* W1   = (const float*)d_in[3];
    const float* att1 = (const float*)d_in[4];
    const float* b1   = (const float*)d_in[5];
    const float* W2   = (const float*)d_in[6];
    const float* att2 = (const float*)d_in[7];
    const float* b2   = (const float*)d_in[8];
    const float* Wq   = (const float*)d_in[9];
    const float* bq   = (const float*)d_in[10];
    const float* Wk   = (const float*)d_in[11];
    const float* bk   = (const float*)d_in[12];
    const float* Wv   = (const float*)d_in[13];
    const float* bv   = (const float*)d_in[14];
    const float* g0   = (const float*)d_in[15];
    const float* be0  = (const float*)d_in[16];
    const float* Wf1  = (const float*)d_in[17];
    const float* bf1  = (const float*)d_in[18];
    const float* Wf2  = (const float*)d_in[19];
    const float* bf2  = (const float*)d_in[20];
    const float* g1   = (const float*)d_in[21];
    const float* be1  = (const float*)d_in[22];
    const float* Wrep = (const float*)d_in[23];
    const float* brep = (const float*)d_in[24];

    const int n = in_sizes[0] / 64;   // 100000
    const int e = in_sizes[1] / 2;    // 1600000
    const int* src = ei;
    const int* dst = ei + e;

    char* ws = (char*)d_ws;
    size_t o = 0;
    auto alloc = [&](size_t bytes) -> void* {
        void* p = ws + o;
        o += (bytes + 255) & ~(size_t)255;
        return p;
    };
    __hip_bfloat16* xw1b = (__hip_bfloat16*)alloc((size_t)n * 64 * 2);
    __hip_bfloat16* h1b  = (__hip_bfloat16*)alloc((size_t)n * 64 * 2);
    __hip_bfloat16* xw2p = (__hip_bfloat16*)alloc((size_t)n * 128 * 2); // packed
    unsigned* ajp = (unsigned*)alloc((size_t)n * 4 * 4);  // packed bf16 aj1
    float* ai1   = (float*)alloc((size_t)n * 8 * 4);
    float* ai2   = (float*)alloc((size_t)n * 8 * 4);
    float* xt    = (float*)alloc((size_t)n * 6 * 4);
    int*   deg   = (int*)  alloc((size_t)n * 4);
    int*   offs  = (int*)  alloc((size_t)n * 4);
    int*   cur   = (int*)  alloc((size_t)n * 4);
    int*   bsum  = (int*)  alloc(256 * 4);
    int*   elist = (int*)  alloc((size_t)e * 4);
    (void)ws_size; (void)n_in; (void)out_size;

    hipMemsetAsync(deg, 0, (size_t)n * 4, stream);
    hipMemsetAsync(cur, 0, (size_t)n * 4, stream);

    const int NB = (n + 1023) / 1024;    // 98 scan blocks

    count_kernel<<<(e + 255) / 256, 256, 0, stream>>>(src, dst, deg, e);
    encoder_kernel<<<n / 8, 256, 0, stream>>>(ef, Wq, bq, Wk, bk, Wv, bv, g0, be0,
                                              Wf1, bf1, Wf2, bf2, g1, be1, Wrep, brep,
                                              xt, n);
    xw1_kernel<<<n / 16, 256, 0, stream>>>(x, W1, att1, xw1b, ai1, ajp, n);
    scan1_kernel<<<NB, 1024, 0, stream>>>(deg, bsum, n);
    scan2_kernel<<<1, 128, 0, stream>>>(bsum, NB);
    scan3_kernel<<<NB, 1024, 0, stream>>>(deg, bsum, offs, n);
    scatter_kernel<<<(e + 255) / 256, 256, 0, stream>>>(src, dst, offs, cur, elist, e);
    agg1_kernel<<<n / 4, 256, 0, stream>>>(xw1b, ai1, ajp, att1, b1,
                                           offs, deg, elist, h1b, n);
    xw2pack_kernel<<<n / 16, 256, 0, stream>>>(h1b, xt, W2, att2, xw2p, ai2, n);
    agg2_kernel<<<n / 4, 256, 0, stream>>>((const unsigned*)xw2p, ai2, b2,
                                           offs, deg, elist, (float*)d_out, n);
}